// Round 3
// baseline (140.717 us; speedup 1.0000x reference)
//
#include <hip/hip_runtime.h>

#define N_ROWS 16384
#define NCB    16
#define CB     1024
#define TPB    256          // 1 row per thread; grid (16, 64) = 4 blocks/CU

// Zeros the 4 scalar tail outputs (rate_uem accumulator + 3 literal zeros).
__global__ void zero_tail_kernel(float* p) {
    int t = threadIdx.x;
    if (t < 4) p[t] = 0.0f;
}

// Per group a: softmax over logits -> write cnb = ||c||^2 + (-log2 pmf)/lambda
// and l2u = -log2 pmf into workspace. One block per group.
__global__ __launch_bounds__(256) void prep_kernel(
    const float4* __restrict__ cbook,
    const float*  __restrict__ logits,
    const float*  __restrict__ lmbda_p,
    float* __restrict__ ws_cnb,
    float* __restrict__ ws_l2u)
{
    const int a = blockIdx.x;
    const int t = threadIdx.x;
    __shared__ float sredA[4], sredB[4];

    float l[4];
    float m = -INFINITY;
#pragma unroll
    for (int r = 0; r < 4; ++r) {
        l[r] = logits[a * CB + t + 256 * r];
        m = fmaxf(m, l[r]);
    }
#pragma unroll
    for (int off = 32; off >= 1; off >>= 1) m = fmaxf(m, __shfl_down(m, off, 64));
    if ((t & 63) == 0) sredA[t >> 6] = m;
    __syncthreads();
    const float gmax = fmaxf(fmaxf(sredA[0], sredA[1]), fmaxf(sredA[2], sredA[3]));

    float s = 0.f;
#pragma unroll
    for (int r = 0; r < 4; ++r) s += __expf(l[r] - gmax);
#pragma unroll
    for (int off = 32; off >= 1; off >>= 1) s += __shfl_down(s, off, 64);
    if ((t & 63) == 0) sredB[t >> 6] = s;
    __syncthreads();
    const float lse   = gmax + __logf(sredB[0] + sredB[1] + sredB[2] + sredB[3]);
    const float inv_l = 1.0f / lmbda_p[0];
    const float INV_LN2 = 1.4426950408889634f;
#pragma unroll
    for (int r = 0; r < 4; ++r) {
        int i = t + 256 * r;
        float4 w = cbook[a * CB + i];
        float v  = (lse - l[r]) * INV_LN2;           // -log2 pmf  (>= 0)
        ws_l2u[a * CB + i] = v;
        ws_cnb[a * CB + i] = w.x * w.x + w.y * w.y + w.z * w.z + w.w * w.w
                           + v * inv_l;              // ||c||^2 + rate_bias
    }
}

__global__ __launch_bounds__(TPB) void ecvq_kernel(
    const float4* __restrict__ x,       // (N*NCB) float4 rows of dim 4
    const float4* __restrict__ cbook,   // (NCB*CB) float4 codewords
    const float*  __restrict__ ws_cnb,  // (NCB*CB) ||c||^2 + rate_bias
    const float*  __restrict__ ws_l2u,  // (NCB*CB) -log2 pmf
    float4* __restrict__ xhat,          // (N*NCB) float4
    float*  __restrict__ tail)
{
    __shared__ float4 s_cb[CB];    // epilogue gather only (16 KB)
    __shared__ float  s_l2u[CB];   // epilogue gather only ( 4 KB)

    const int a     = blockIdx.x;   // codebook group 0..15
    const int chunk = blockIdx.y;   // row chunk 0..63 (256 rows each)
    const int t     = threadIdx.x;

    // stage tables for the per-row epilogue gather
#pragma unroll
    for (int r = 0; r < CB / TPB; ++r) {
        int i = t + TPB * r;
        s_cb[i]  = cbook[a * CB + i];
        s_l2u[i] = ws_l2u[a * CB + i];
    }

    // this thread's row, pre-scaled by -2 so dist = dot + base
    const int n = chunk * TPB + t;
    const float4 xv = x[n * NCB + a];
    const float4 xm2 = make_float4(-2.f * xv.x, -2.f * xv.y,
                                   -2.f * xv.z, -2.f * xv.w);
    __syncthreads();

    // hot loop: codeword stream is wave-uniform -> scalar (SMEM) loads,
    // zero LDS traffic.
    const float4* __restrict__ cb  = cbook  + a * CB;
    const float*  __restrict__ cnb = ws_cnb + a * CB;

    float dmin = INFINITY;
    int   imin = 0;
#pragma unroll 8
    for (int c = 0; c < CB; ++c) {
        const float4 w = cb[c];
        float d = xm2.x * w.x;
        d = fmaf(xm2.y, w.y, d);
        d = fmaf(xm2.z, w.z, d);
        d = fmaf(xm2.w, w.w, d);
        d += cnb[c];
        bool lt = d < dmin;        // strict '<': first index on ties (argmin)
        dmin = lt ? d : dmin;
        imin = lt ? c : imin;
    }

    // epilogue: gather winning codeword + accumulate rate
    xhat[n * NCB + a] = s_cb[imin];
    float rsum = s_l2u[imin];
#pragma unroll
    for (int off = 32; off >= 1; off >>= 1) rsum += __shfl_down(rsum, off, 64);
    __shared__ float wsum[TPB / 64];
    if ((t & 63) == 0) wsum[t >> 6] = rsum;
    __syncthreads();
    if (t == 0) {
        float tot = wsum[0];
#pragma unroll
        for (int w = 1; w < TPB / 64; ++w) tot += wsum[w];
        atomicAdd(&tail[0], tot);
    }
}

extern "C" void kernel_launch(void* const* d_in, const int* in_sizes, int n_in,
                              void* d_out, int out_size, void* d_ws, size_t ws_size,
                              hipStream_t stream) {
    (void)in_sizes; (void)n_in; (void)out_size; (void)ws_size;
    const float4* x      = (const float4*)d_in[0];
    const float4* cbook  = (const float4*)d_in[1];
    const float*  logits = (const float*)d_in[2];
    const float*  lmbda  = (const float*)d_in[3];

    float* out  = (float*)d_out;
    float* tail = out + (size_t)N_ROWS * NCB * 4;   // offset 1048576

    float* ws_cnb = (float*)d_ws;                   // 16*1024 floats
    float* ws_l2u = ws_cnb + NCB * CB;              // 16*1024 floats (128 KB total)

    zero_tail_kernel<<<1, 64, 0, stream>>>(tail);
    prep_kernel<<<NCB, 256, 0, stream>>>(cbook, logits, lmbda, ws_cnb, ws_l2u);

    dim3 grid(NCB, N_ROWS / TPB);                   // (16, 64) = 1024 blocks
    ecvq_kernel<<<grid, TPB, 0, stream>>>(x, cbook, ws_cnb, ws_l2u,
                                          (float4*)d_out, tail);
}